// Round 15
// baseline (528.373 us; speedup 1.0000x reference)
//
#include <hip/hip_runtime.h>
#include <hip/hip_bf16.h>

// Problem: S=1024, B=512, F=128, H=3
//   xp[s,b,h] = dot(x[s,b,:], W_ih[h,:]) + b_ih[h] + b_hh[h]   (bias folded)
//   h_t = tanh(xp[t] + W_hh @ h_{t-1})
//   delta[s,b] = signal[argmax_h(h[s,b,:] + gumbel[s,b,:])]   (hard gumbel fwd)
//   out = [delta (S*B floats), h_T (B*3 floats)]

#define S_DIM 1024
#define B_DIM 512
#define F_DIM 128
#define TILE_S 8
#define NT (S_DIM / TILE_S)   // 128 tiles

// ---------------- Kernel 1: input projection + gumbel pack ------------------
// EXACT round-3 version (known-good: part of the 480 µs config; R11's nt/8-lane
// variant regressed +40 µs). 32 lanes per row, contiguous 1KB/instr loads.
__global__ __launch_bounds__(256) void k_inproj(
    const float* __restrict__ x,       // (S,B,F)
    const float* __restrict__ gumbel,  // (S,B,3)
    const float* __restrict__ W,       // (3,128)
    const float* __restrict__ b_ih,    // (3)
    const float* __restrict__ b_hh,    // (3)
    float* __restrict__ xpk)           // (S*B, 8)
{
    int tid = blockIdx.x * 256 + threadIdx.x;
    int row = tid >> 5;                 // 0 .. S*B-1
    int l   = tid & 31;                 // float4 chunk within the row

    float4 w0 = ((const float4*)(W))[l];
    float4 w1 = ((const float4*)(W + F_DIM))[l];
    float4 w2 = ((const float4*)(W + 2 * F_DIM))[l];

    float4 v = ((const float4*)x)[(size_t)row * 32 + l];

    float p0 = v.x * w0.x + v.y * w0.y + v.z * w0.z + v.w * w0.w;
    float p1 = v.x * w1.x + v.y * w1.y + v.z * w1.z + v.w * w1.w;
    float p2 = v.x * w2.x + v.y * w2.y + v.z * w2.z + v.w * w2.w;

#pragma unroll
    for (int m = 1; m <= 16; m <<= 1) {
        p0 += __shfl_xor(p0, m, 64);
        p1 += __shfl_xor(p1, m, 64);
        p2 += __shfl_xor(p2, m, 64);
    }

    if (l < 3) {
        float a = (l == 0) ? p0 : ((l == 1) ? p1 : p2);
        xpk[(size_t)row * 8 + l] = a + b_ih[l] + b_hh[l];
    } else if (l >= 4 && l < 7) {
        xpk[(size_t)row * 8 + l] = gumbel[(size_t)row * 3 + (l - 4)];
    }
}

// ---------------- Kernel 2: LDS-staged scan (3-buffer, counted vmcnt) -------
__device__ __forceinline__ float tanh_fast(float xv) {
    float e = __expf(2.0f * xv);
    return 1.0f - 2.0f * __builtin_amdgcn_rcpf(e + 1.0f);
}

// s_waitcnt immediates (gfx9 encoding): vmcnt lo4 [3:0], hi2 [15:14];
// lgkm=0xF<<8 (no wait), exp=0x7<<4 (no wait).
#define WAITCNT_VM16 0x4F70   // vmcnt(16)
#define WAITCNT_VM24 0x4F78   // vmcnt(24)
#define WAITCNT_VM8  0x0F78   // vmcnt(8)

typedef __attribute__((address_space(1))) const void gas_void;
typedef __attribute__((address_space(3))) void las_void;

__global__ __launch_bounds__(64) void k_scan(
    const float* __restrict__ xpk,     // (S*B, 8) packed: xp[0..2] | g[4..6]
    const float* __restrict__ W_hh,    // (3,3)
    const float* __restrict__ signal,  // (3,1)
    float* __restrict__ out)           // [S*B delta] ++ [B*3 hidden]
{
    // 3 buffers x 8 steps x 64 batch x 32B = 48 KB
    __shared__ float lds[3 * TILE_S * 512];

    int tid = threadIdx.x;            // 0..63 = lane = local batch
    int b0  = blockIdx.x * 64;
    int b   = b0 + tid;

    // Source swizzle for global_load_lds (linear LDS dest: slot = lane).
    // Slot s holds global 16B chunk (b_g = s>>1, half = (s&1)^((s>>3)&1)):
    // spreads the reader's stride-32B ds_read_b128 over all 8 bank-quads.
    int hsw   = (tid & 1) ^ ((tid >> 3) & 1);
    int goffA = ((tid >> 1) * 32) + (hsw << 4);        // bytes in 2KB step-row
    int goffB = ((32 + (tid >> 1)) * 32) + (hsw << 4);
    // Reader: lane b's xp half at float idx b*8 + x*4, g half at b*8 + (x^1)*4.
    int x   = (tid >> 2) & 1;
    int rdx = tid * 8 + (x << 2);
    int rdg = tid * 8 + ((x ^ 1) << 2);

    float w00 = W_hh[0], w01 = W_hh[1], w02 = W_hh[2];
    float w10 = W_hh[3], w11 = W_hh[4], w12 = W_hh[5];
    float w20 = W_hh[6], w21 = W_hh[7], w22 = W_hh[8];
    float s0v = signal[0], s1v = signal[1], s2v = signal[2];

    float h0 = 0.f, h1 = 0.f, h2 = 0.f;

    const char* xpc = (const char*)xpk;

    auto issue_tile = [&](int t, int buf) {
        const char* gtile = xpc + (((size_t)t * TILE_S * B_DIM) + b0) * 32;
        float* lb = &lds[buf * (TILE_S * 512)];
#pragma unroll
        for (int i = 0; i < TILE_S; ++i) {
            const char* gs = gtile + (size_t)i * (B_DIM * 32);
            __builtin_amdgcn_global_load_lds(
                (gas_void*)(gs + goffA), (las_void*)(lb + i * 512),       16, 0, 0);
            __builtin_amdgcn_global_load_lds(
                (gas_void*)(gs + goffB), (las_void*)(lb + i * 512 + 256), 16, 0, 0);
        }
    };

    // Prologue: 2 tiles in flight (32 outstanding loads).
    issue_tile(0, 0);
    issue_tile(1, 1);

    int bufc = 0;
    for (int t = 0; t < NT; ++t) {
        // Wait until THIS tile's 16 loads retired (in-order vmcnt retirement).
        // Steady state: newer ops = 8 stores(t-1) + 16 loads(t+1) = 24.
        if (t == 0)           __builtin_amdgcn_s_waitcnt(WAITCNT_VM16);
        else if (t == NT - 1) __builtin_amdgcn_s_waitcnt(WAITCNT_VM8);
        else                  __builtin_amdgcn_s_waitcnt(WAITCNT_VM24);
        __builtin_amdgcn_sched_barrier(0);

        const float* lb = &lds[bufc * (TILE_S * 512)];
#pragma unroll
        for (int i = 0; i < TILE_S; ++i) {
            float4 xv = *(const float4*)(lb + i * 512 + rdx);
            float4 gv = *(const float4*)(lb + i * 512 + rdg);
            float a0 = xv.x + w00 * h0 + w01 * h1 + w02 * h2;
            float a1 = xv.y + w10 * h0 + w11 * h1 + w12 * h2;
            float a2 = xv.z + w20 * h0 + w21 * h1 + w22 * h2;
            h0 = tanh_fast(a0);
            h1 = tanh_fast(a1);
            h2 = tanh_fast(a2);
            float l0 = h0 + gv.x, l1 = h1 + gv.y, l2 = h2 + gv.z;
            float d = (l2 > l0 && l2 > l1) ? s2v : ((l1 > l0) ? s1v : s0v);
            out[(t * TILE_S + i) * B_DIM + b] = d;
        }
        __builtin_amdgcn_sched_barrier(0);

        if (t + 2 < NT) issue_tile(t + 2, (t + 2) % 3);
        bufc = (bufc == 2) ? 0 : bufc + 1;
    }

    float* hid = out + (size_t)S_DIM * B_DIM + (size_t)b * 3;
    hid[0] = h0; hid[1] = h1; hid[2] = h2;
}

extern "C" void kernel_launch(void* const* d_in, const int* in_sizes, int n_in,
                              void* d_out, int out_size, void* d_ws, size_t ws_size,
                              hipStream_t stream) {
    const float* x      = (const float*)d_in[0];
    const float* gumbel = (const float*)d_in[1];
    const float* W_ih   = (const float*)d_in[2];
    const float* W_hh   = (const float*)d_in[3];
    const float* b_ih   = (const float*)d_in[4];
    const float* b_hh   = (const float*)d_in[5];
    const float* signal = (const float*)d_in[6];

    float* xpk = (float*)d_ws;                    // S*B*8 floats = 16 MB
    float* out = (float*)d_out;

    // 32 lanes per row -> S*B*32 threads.
    k_inproj<<<(S_DIM * B_DIM * 32) / 256, 256, 0, stream>>>(
        x, gumbel, W_ih, b_ih, b_hh, xpk);
    k_scan<<<B_DIM / 64, 64, 0, stream>>>(xpk, W_hh, signal, out);
}